// Round 11
// baseline (272.838 us; speedup 1.0000x reference)
//
#include <hip/hip_runtime.h>

// DualEmbedding v11 — MERGED kernel via linearity:
//   0.5*(h[src]+h[dst]) = (0.5*W_node)@x[src] + (0.5*W_node)@x[dst] + b_node
// so the edge kernel computes the endpoint term with 2 extra MFMA passes over
// gathered bf16 x_node rows. The node MFMA kernel is replaced by a trivial
// f32->bf16 cast (natural layout == B-fragment layout). Removes the h_node
// write/read round trip + inter-kernel barrier; endpoint term now f32-accum
// (better precision than the old bf16 h table).
//
// Kernel A (cast): x_node_bf16[n][k] = bf16(x_node[n][k])     (~77 MB, ~13us)
// Kernel B (edge): out = LN(x_e@We.T + b_e + 0.5Wn@(xs) + 0.5Wn@(xd) + b_n)
//
// MFMA mapping (16x16x32 bf16): C tile tt, lane(c=lane&15,g=lane>>4), reg j =
//   C[dim=16tt+4g+j][edge e0+c] -> each lane owns all 128 dims of ONE edge.
// B-fragment slice s: lane(c,g) elem j = x[row][32s+8g+j]  (natural layout:
//   16B/lane, 4 lanes cover a contiguous 64B line per row per instr).
// LDS W swizzle: row r, 8-bf16 slot sigma stored at sigma^(r&7) — 0 bank
// conflicts measured (R4/R6).

typedef __attribute__((ext_vector_type(8))) short bf16x8;
typedef __attribute__((ext_vector_type(4))) float f32x4;

__device__ __forceinline__ short f2bf(float f) {          // RTNE f32->bf16
  unsigned u = __float_as_uint(f);
  u = (u + 0x7FFFu + ((u >> 16) & 1u)) >> 16;
  return (short)u;
}
__device__ __forceinline__ float bf2f(short s) {
  return __uint_as_float(((unsigned)(unsigned short)s) << 16);
}
__device__ __forceinline__ bf16x8 cvt8(const float* __restrict__ p) {
  const f32x4 a = *(const f32x4*)p;
  const f32x4 b = *(const f32x4*)(p + 4);
  bf16x8 r;
  r[0] = f2bf(a[0]); r[1] = f2bf(a[1]); r[2] = f2bf(a[2]); r[3] = f2bf(a[3]);
  r[4] = f2bf(b[0]); r[5] = f2bf(b[1]); r[6] = f2bf(b[2]); r[7] = f2bf(b[3]);
  return r;
}
__device__ __forceinline__ bf16x8 cvt8s(const float* __restrict__ p, float sc) {
  const f32x4 a = *(const f32x4*)p;
  const f32x4 b = *(const f32x4*)(p + 4);
  bf16x8 r;
  r[0] = f2bf(sc * a[0]); r[1] = f2bf(sc * a[1]);
  r[2] = f2bf(sc * a[2]); r[3] = f2bf(sc * a[3]);
  r[4] = f2bf(sc * b[0]); r[5] = f2bf(sc * b[1]);
  r[6] = f2bf(sc * b[2]); r[7] = f2bf(sc * b[3]);
  return r;
}

// ---------------- cast: x_node f32 -> bf16, natural layout -----------------
__global__ __launch_bounds__(256) void cast_node_kernel(
    const float* __restrict__ x, short* __restrict__ y, int nchunks)
{
  int i = blockIdx.x * 256 + threadIdx.x;
  const int stride = gridDim.x * 256;
  for (; i < nchunks; i += stride)
    *(bf16x8*)(y + (size_t)i * 8) = cvt8(x + (size_t)i * 8);
}

// ---------------- merged edge kernel ---------------------------------------
__global__ __launch_bounds__(256) void edge_merged_kernel(
    const float* __restrict__ x_edge,
    const int*   __restrict__ eidx,      // [2, E] int32
    const float* __restrict__ W_edge,
    const float* __restrict__ b_edge,
    const float* __restrict__ W_node,
    const float* __restrict__ b_node,
    const short* __restrict__ xnb,       // [N][128] bf16 (cast kernel output)
    const float* __restrict__ gamma,
    const float* __restrict__ beta,
    float* __restrict__ out,
    int n_edges)
{
  __shared__ short Wn[16384];           // 0.5*W_node, 128x128 bf16, swizzled
  __shared__ short We[8192];            // W_edge, 128x64 bf16, swizzled
  __shared__ float plds[384];           // (b_edge+b_node) | gamma | beta

  const int tid = threadIdx.x;
  {
    const int r = tid >> 1, h = tid & 1;
    const float* we = W_edge + (size_t)r * 64 + 32 * h;
#pragma unroll
    for (int q = 0; q < 4; ++q) {
      const bf16x8 v = cvt8(we + 8 * q);
      const int slot = (4 * h + q) ^ (r & 7);
      *(bf16x8*)(&We[r * 64 + slot * 8]) = v;
    }
    const float* wn = W_node + (size_t)r * 128 + 64 * h;
#pragma unroll
    for (int q = 0; q < 8; ++q) {
      const bf16x8 v = cvt8s(wn + 8 * q, 0.5f);
      const int slot = (8 * h + q) ^ (r & 7);
      *(bf16x8*)(&Wn[r * 128 + slot * 8]) = v;
    }
    if (tid < 128) {
      plds[tid]       = b_edge[tid] + b_node[tid];
      plds[128 + tid] = gamma[tid];
      plds[256 + tid] = beta[tid];
    }
  }
  __syncthreads();

  const int lane = tid & 63;
  const int c = lane & 15, g = lane >> 4;
  const int gw = blockIdx.x * 4 + (tid >> 6);
  const int nw = gridDim.x * 4;
  const int ntiles = (n_edges + 15) >> 4;

  const int we0 = c * 64 + ((g) ^ (c & 7)) * 8;
  const int we1 = c * 64 + ((4 + g) ^ (c & 7)) * 8;
  int wn_off[4];
#pragma unroll
  for (int s = 0; s < 4; ++s) wn_off[s] = c * 128 + ((4 * s + g) ^ (c & 7)) * 8;

  if (gw >= ntiles) return;

  auto LOADIDX = [&](int tile, int& src, int& dst) {
    const int e = (tile * 16 + c < n_edges) ? tile * 16 + c : n_edges - 1;
    src = eidx[e];
    dst = eidx[n_edges + e];
  };
  auto LOADX = [&](int tile, bf16x8& b0, bf16x8& b1) {
    const int e = (tile * 16 + c < n_edges) ? tile * 16 + c : n_edges - 1;
    const float* xr = x_edge + (size_t)e * 64;
    b0 = cvt8(xr + 8 * g);
    b1 = cvt8(xr + 32 + 8 * g);
  };
  auto GATHER = [&](int src, int dst, bf16x8* xs, bf16x8* xd) {
    // per instr s: 16 rows x (4 lanes x 16B = contiguous 64B) per row
    const short* ps = xnb + (size_t)src * 128 + g * 8;
    const short* pd = xnb + (size_t)dst * 128 + g * 8;
#pragma unroll
    for (int s = 0; s < 4; ++s) {
      xs[s] = *(const bf16x8*)(ps + 32 * s);
      xd[s] = *(const bf16x8*)(pd + 32 * s);
    }
  };

  // ---- pipeline state ----------------------------------------------------
  bf16x8 bx0, bx1, bxN0, bxN1;
  bf16x8 xs[4], xd[4];
  int srcN, dstN;

  {
    int src0, dst0;
    LOADIDX(gw, src0, dst0);
    LOADX(gw, bx0, bx1);
    GATHER(src0, dst0, xs, xd);
    LOADIDX(gw + nw, srcN, dstN);
  }

  for (int t = gw; t < ntiles; t += nw) {
    f32x4 acc[8];
#pragma unroll
    for (int tt = 0; tt < 8; ++tt)
      acc[tt] = *(const f32x4*)(plds + 16 * tt + 4 * g);

    // 1) node-endpoint MFMAs (consume xs/xd gathered one iteration ago);
    //    s-outer, tt-inner: dependent MFMAs to same acc separated by 8
#pragma unroll
    for (int s = 0; s < 4; ++s) {
      bf16x8 a[8];
#pragma unroll
      for (int tt = 0; tt < 8; ++tt)
        a[tt] = *(const bf16x8*)(&Wn[tt * 2048 + wn_off[s]]);
#pragma unroll
      for (int tt = 0; tt < 8; ++tt)
        acc[tt] = __builtin_amdgcn_mfma_f32_16x16x32_bf16(a[tt], xs[s], acc[tt], 0, 0, 0);
#pragma unroll
      for (int tt = 0; tt < 8; ++tt)
        acc[tt] = __builtin_amdgcn_mfma_f32_16x16x32_bf16(a[tt], xd[s], acc[tt], 0, 0, 0);
    }

    // 2) xs/xd free -> issue gathers for tile t+nw; prefetch idx and x
    GATHER(srcN, dstN, xs, xd);
    LOADIDX(t + 2 * nw, srcN, dstN);
    LOADX(t + nw, bxN0, bxN1);

    // 3) edge GEMM
#pragma unroll
    for (int tt = 0; tt < 8; ++tt) {
      const bf16x8 a0 = *(const bf16x8*)(&We[tt * 1024 + we0]);
      const bf16x8 a1 = *(const bf16x8*)(&We[tt * 1024 + we1]);
      acc[tt] = __builtin_amdgcn_mfma_f32_16x16x32_bf16(a0, bx0, acc[tt], 0, 0, 0);
      acc[tt] = __builtin_amdgcn_mfma_f32_16x16x32_bf16(a1, bx1, acc[tt], 0, 0, 0);
    }

    // 4) LayerNorm (dims of one edge split over lanes c, c+16, c+32, c+48)
    float s1 = 0.f;
#pragma unroll
    for (int tt = 0; tt < 8; ++tt)
      s1 += (acc[tt][0] + acc[tt][1]) + (acc[tt][2] + acc[tt][3]);
    s1 += __shfl_xor(s1, 16, 64);
    s1 += __shfl_xor(s1, 32, 64);
    const float mu = s1 * (1.f / 128.f);

    float s2 = 0.f;
#pragma unroll
    for (int tt = 0; tt < 8; ++tt)
#pragma unroll
      for (int j = 0; j < 4; ++j) {
        const float d = acc[tt][j] - mu;
        acc[tt][j] = d;
        s2 = fmaf(d, d, s2);
      }
    s2 += __shfl_xor(s2, 16, 64);
    s2 += __shfl_xor(s2, 32, 64);
    const float rstd = rsqrtf(s2 * (1.f / 128.f) + 1e-5f);

    // 5) store
    if (t * 16 + c < n_edges) {
      float* o = out + (size_t)(t * 16 + c) * 128 + 4 * g;
#pragma unroll
      for (int tt = 0; tt < 8; ++tt) {
        f32x4 r;
#pragma unroll
        for (int j = 0; j < 4; ++j)
          r[j] = fmaf(acc[tt][j] * rstd, plds[128 + 16 * tt + 4 * g + j],
                      plds[256 + 16 * tt + 4 * g + j]);
        *(f32x4*)(o + 16 * tt) = r;
      }
    }

    // 6) rotate x prefetch
    bx0 = bxN0; bx1 = bxN1;
  }
}

extern "C" void kernel_launch(void* const* d_in, const int* in_sizes, int n_in,
                              void* d_out, int out_size, void* d_ws, size_t ws_size,
                              hipStream_t stream) {
  const float* x_node = (const float*)d_in[0];
  const float* x_edge = (const float*)d_in[1];
  const int*   eidx   = (const int*)  d_in[2];
  const float* W_edge = (const float*)d_in[3];
  const float* b_edge = (const float*)d_in[4];
  const float* W_node = (const float*)d_in[5];
  const float* b_node = (const float*)d_in[6];
  const float* gamma  = (const float*)d_in[7];
  const float* beta   = (const float*)d_in[8];
  float* out = (float*)d_out;

  const int n_nodes = in_sizes[0] / 128;
  const int n_edges = in_sizes[2] / 2;

  short* xnb = (short*)d_ws;            // bf16 x_node table, 25.6 MB
  if (ws_size < (size_t)n_nodes * 128 * sizeof(short)) return;  // ws too small

  const int nchunks = n_nodes * 16;     // 8 elems per chunk
  cast_node_kernel<<<2048, 256, 0, stream>>>(x_node, xnb, nchunks);
  edge_merged_kernel<<<2048, 256, 0, stream>>>(x_edge, eidx, W_edge, b_edge,
                                               W_node, b_node, xnb,
                                               gamma, beta, out, n_edges);
}

// Round 12
// 259.167 us; speedup vs baseline: 1.0528x; 1.0528x over previous
//
#include <hip/hip_runtime.h>

// DualEmbedding v12 — v9 (champion, 247us) + 2-DEEP gather pipeline:
// gathers issued TWO iterations before consumption (A/B register sets),
// idx prefetched three ahead. Everything else identical to v9.
// (v11 merge reverted: 5x MFMA in hot loop cost +25us.)
//
// Kernel A (node): h_node_bf16[node]: chunk(g,k) at byte k*64+g*16 holds
//   dims {16*(2k)+4g+j, 16*(2k+1)+4g+j}, j=0..3 (bf16).
// Kernel B (edge): out = LN(x_edge @ W_edge.T + b_edge + 0.5*(h[src]+h[dst]))
//
// MFMA mapping (16x16x32 bf16): C tile t, lane(c=lane&15,g=lane>>4), reg j =
//   C[dim=16t+4g+j][row base+c]  -> each lane owns all 128 dims of ONE row.
// LDS W swizzle: row r, slot sigma at sigma^(r&7) — 0 bank conflicts (R4/R6).

typedef __attribute__((ext_vector_type(8))) short bf16x8;
typedef __attribute__((ext_vector_type(4))) float f32x4;

__device__ __forceinline__ short f2bf(float f) {          // RTNE f32->bf16
  unsigned u = __float_as_uint(f);
  u = (u + 0x7FFFu + ((u >> 16) & 1u)) >> 16;
  return (short)u;
}
__device__ __forceinline__ float bf2f(short s) {
  return __uint_as_float(((unsigned)(unsigned short)s) << 16);
}
__device__ __forceinline__ bf16x8 cvt8(const float* __restrict__ p) {
  const f32x4 a = *(const f32x4*)p;
  const f32x4 b = *(const f32x4*)(p + 4);
  bf16x8 r;
  r[0] = f2bf(a[0]); r[1] = f2bf(a[1]); r[2] = f2bf(a[2]); r[3] = f2bf(a[3]);
  r[4] = f2bf(b[0]); r[5] = f2bf(b[1]); r[6] = f2bf(b[2]); r[7] = f2bf(b[3]);
  return r;
}

// ---------------- node projection -> permuted bf16 table -------------------
__global__ __launch_bounds__(256) void node_mfma_kernel(
    const float* __restrict__ x_node,
    const float* __restrict__ W_node,
    const float* __restrict__ b_node,
    short* __restrict__ h_node,          // [N][128] bf16, (k,g)-chunked
    int n_nodes)
{
  __shared__ short Wlds[16384];         // 128 rows x 128 bf16 = 32 KB, swizzled
  __shared__ float blds[128];

  const int tid = threadIdx.x;
  {
    const int r = tid >> 1, h = tid & 1;
    const float* wr = W_node + (size_t)r * 128 + 64 * h;
#pragma unroll
    for (int q = 0; q < 8; ++q) {
      const bf16x8 v = cvt8(wr + 8 * q);
      const int slot = (8 * h + q) ^ (r & 7);
      *(bf16x8*)(&Wlds[r * 128 + slot * 8]) = v;
    }
    if (tid < 128) blds[tid] = b_node[tid];
  }
  __syncthreads();

  const int lane = tid & 63;
  const int c = lane & 15, g = lane >> 4;
  const int gw = blockIdx.x * 4 + (tid >> 6);
  const int nw = gridDim.x * 4;
  const int ntiles = (n_nodes + 15) >> 4;

  int woff[4];
#pragma unroll
  for (int s = 0; s < 4; ++s) woff[s] = c * 128 + ((4 * s + g) ^ (c & 7)) * 8;

  for (int tile = gw; tile < ntiles; tile += nw) {
    const int n0 = tile << 4;
    const int n = (n0 + c < n_nodes) ? n0 + c : n_nodes - 1;
    const float* xr = x_node + (size_t)n * 128;
    bf16x8 bx[4];
#pragma unroll
    for (int s = 0; s < 4; ++s) bx[s] = cvt8(xr + 32 * s + 8 * g);

    f32x4 acc[8];
#pragma unroll
    for (int t = 0; t < 8; ++t)
      acc[t] = *(const f32x4*)(blds + 16 * t + 4 * g);
#pragma unroll
    for (int t = 0; t < 8; ++t)
#pragma unroll
      for (int s = 0; s < 4; ++s) {
        const bf16x8 a = *(const bf16x8*)(&Wlds[t * 2048 + woff[s]]);
        acc[t] = __builtin_amdgcn_mfma_f32_16x16x32_bf16(a, bx[s], acc[t], 0, 0, 0);
      }

    if (n0 + c < n_nodes) {
      short* o = h_node + (size_t)(n0 + c) * 128 + g * 8;
#pragma unroll
      for (int k = 0; k < 4; ++k) {
        bf16x8 v;
#pragma unroll
        for (int j = 0; j < 4; ++j) {
          v[j]     = f2bf(acc[2 * k][j]);
          v[4 + j] = f2bf(acc[2 * k + 1][j]);
        }
        *(bf16x8*)(o + 32 * k) = v;
      }
    }
  }
}

// ---------------- fused edge: GEMM + gather + LayerNorm --------------------
__global__ __launch_bounds__(256) void edge_mfma_kernel(
    const float* __restrict__ x_edge,
    const int*   __restrict__ eidx,      // [2, E] int32
    const float* __restrict__ W_edge,
    const float* __restrict__ b_edge,
    const short* __restrict__ h_node,    // permuted bf16, (k,g)-chunked
    const float* __restrict__ gamma,
    const float* __restrict__ beta,
    float* __restrict__ out,
    int n_edges)
{
  __shared__ short Wlds[8192];          // 128 rows x 64 bf16 = 16 KB, swizzled
  __shared__ float plds[384];           // bias | gamma | beta

  const int tid = threadIdx.x;
  {
    const int r = tid >> 1, h = tid & 1;
    const float* wr = W_edge + (size_t)r * 64 + 32 * h;
#pragma unroll
    for (int q = 0; q < 4; ++q) {
      const bf16x8 v = cvt8(wr + 8 * q);
      const int slot = (4 * h + q) ^ (r & 7);
      *(bf16x8*)(&Wlds[r * 64 + slot * 8]) = v;
    }
    if (tid < 128) {
      plds[tid]       = b_edge[tid];
      plds[128 + tid] = gamma[tid];
      plds[256 + tid] = beta[tid];
    }
  }
  __syncthreads();

  const int lane = tid & 63;
  const int c = lane & 15, g = lane >> 4;
  const int gw = blockIdx.x * 4 + (tid >> 6);
  const int nw = gridDim.x * 4;
  const int ntiles = (n_edges + 15) >> 4;

  const int w0off = c * 64 + ((g) ^ (c & 7)) * 8;
  const int w1off = c * 64 + ((4 + g) ^ (c & 7)) * 8;

  if (gw >= ntiles) return;

  auto LOADIDX = [&](int tile, int& src, int& dst) {
    const int e = (tile * 16 + c < n_edges) ? tile * 16 + c : n_edges - 1;
    src = eidx[e];
    dst = eidx[n_edges + e];
  };
  auto LOADX = [&](int tile, bf16x8& b0, bf16x8& b1) {
    const int e = (tile * 16 + c < n_edges) ? tile * 16 + c : n_edges - 1;
    const float* xr = x_edge + (size_t)e * 64;
    b0 = cvt8(xr + 8 * g);
    b1 = cvt8(xr + 32 + 8 * g);
  };
  auto GATHER = [&](int src, int dst, bf16x8* vs, bf16x8* vd) {
    const short* hs = h_node + (size_t)src * 128 + g * 8;
    const short* hd = h_node + (size_t)dst * 128 + g * 8;
#pragma unroll
    for (int k = 0; k < 4; ++k) {
      vs[k] = *(const bf16x8*)(hs + 32 * k);
      vd[k] = *(const bf16x8*)(hd + 32 * k);
    }
  };
  // consume a gather set + run the rest of one tile
  auto BODY = [&](int t, bf16x8 b0, bf16x8 b1, bf16x8* vs, bf16x8* vd) {
    f32x4 acc[8];
#pragma unroll
    for (int k = 0; k < 4; ++k)
#pragma unroll
      for (int j = 0; j < 4; ++j) {
        acc[2 * k][j]     = plds[16 * (2 * k) + 4 * g + j]
                          + 0.5f * (bf2f(vs[k][j]) + bf2f(vd[k][j]));
        acc[2 * k + 1][j] = plds[16 * (2 * k + 1) + 4 * g + j]
                          + 0.5f * (bf2f(vs[k][4 + j]) + bf2f(vd[k][4 + j]));
      }
#pragma unroll
    for (int tt = 0; tt < 8; ++tt) {
      const bf16x8 a0 = *(const bf16x8*)(&Wlds[tt * 1024 + w0off]);
      const bf16x8 a1 = *(const bf16x8*)(&Wlds[tt * 1024 + w1off]);
      acc[tt] = __builtin_amdgcn_mfma_f32_16x16x32_bf16(a0, b0, acc[tt], 0, 0, 0);
      acc[tt] = __builtin_amdgcn_mfma_f32_16x16x32_bf16(a1, b1, acc[tt], 0, 0, 0);
    }
    float s1 = 0.f;
#pragma unroll
    for (int tt = 0; tt < 8; ++tt)
      s1 += (acc[tt][0] + acc[tt][1]) + (acc[tt][2] + acc[tt][3]);
    s1 += __shfl_xor(s1, 16, 64);
    s1 += __shfl_xor(s1, 32, 64);
    const float mu = s1 * (1.f / 128.f);

    float s2 = 0.f;
#pragma unroll
    for (int tt = 0; tt < 8; ++tt)
#pragma unroll
      for (int j = 0; j < 4; ++j) {
        const float d = acc[tt][j] - mu;
        acc[tt][j] = d;
        s2 = fmaf(d, d, s2);
      }
    s2 += __shfl_xor(s2, 16, 64);
    s2 += __shfl_xor(s2, 32, 64);
    const float rstd = rsqrtf(s2 * (1.f / 128.f) + 1e-5f);

    if (t * 16 + c < n_edges) {
      float* o = out + (size_t)(t * 16 + c) * 128 + 4 * g;
#pragma unroll
      for (int tt = 0; tt < 8; ++tt) {
        f32x4 r;
#pragma unroll
        for (int j = 0; j < 4; ++j)
          r[j] = fmaf(acc[tt][j] * rstd, plds[128 + 16 * tt + 4 * g + j],
                      plds[256 + 16 * tt + 4 * g + j]);
        *(f32x4*)(o + 16 * tt) = r;
      }
    }
  };

  // ---- 2-deep gather pipeline -------------------------------------------
  bf16x8 bx0, bx1, bxN0, bxN1;
  bf16x8 vsA[4], vdA[4], vsB[4], vdB[4];
  int srcC, dstC;

  // prologue: gathers for gw (A) and gw+nw (B) in flight; idx for gw+2nw
  {
    int s0, d0, s1i, d1i;
    LOADIDX(gw, s0, d0);
    GATHER(s0, d0, vsA, vdA);
    LOADIDX(gw + nw, s1i, d1i);
    GATHER(s1i, d1i, vsB, vdB);
    LOADIDX(gw + 2 * nw, srcC, dstC);
    LOADX(gw, bx0, bx1);
    LOADX(gw + nw, bxN0, bxN1);
  }

  int t = gw;
  for (;;) {
    // phase A: consume A (issued 2 iters ago); refill A for t+2nw
    {
      bf16x8 tmpS[4], tmpD[4];
#pragma unroll
      for (int k = 0; k < 4; ++k) { tmpS[k] = vsA[k]; tmpD[k] = vdA[k]; }
      GATHER(srcC, dstC, vsA, vdA);          // gathers for t+2nw
      LOADIDX(t + 3 * nw, srcC, dstC);
      BODY(t, bx0, bx1, tmpS, tmpD);
      LOADX(t + 2 * nw, bx0, bx1);           // x for t+2nw into freed slot
    }
    t += nw;
    if (t >= ntiles) break;

    // phase B: mirror
    {
      bf16x8 tmpS[4], tmpD[4];
#pragma unroll
      for (int k = 0; k < 4; ++k) { tmpS[k] = vsB[k]; tmpD[k] = vdB[k]; }
      GATHER(srcC, dstC, vsB, vdB);
      LOADIDX(t + 3 * nw, srcC, dstC);
      BODY(t, bxN0, bxN1, tmpS, tmpD);
      LOADX(t + 2 * nw, bxN0, bxN1);
    }
    t += nw;
    if (t >= ntiles) break;
  }
}

extern "C" void kernel_launch(void* const* d_in, const int* in_sizes, int n_in,
                              void* d_out, int out_size, void* d_ws, size_t ws_size,
                              hipStream_t stream) {
  const float* x_node = (const float*)d_in[0];
  const float* x_edge = (const float*)d_in[1];
  const int*   eidx   = (const int*)  d_in[2];
  const float* W_edge = (const float*)d_in[3];
  const float* b_edge = (const float*)d_in[4];
  const float* W_node = (const float*)d_in[5];
  const float* b_node = (const float*)d_in[6];
  const float* gamma  = (const float*)d_in[7];
  const float* beta   = (const float*)d_in[8];
  float* out = (float*)d_out;

  const int n_nodes = in_sizes[0] / 128;
  const int n_edges = in_sizes[2] / 2;

  short* h_node = (short*)d_ws;
  if (ws_size < (size_t)n_nodes * 128 * sizeof(short)) return;  // ws too small

  node_mfma_kernel<<<512, 256, 0, stream>>>(x_node, W_node, b_node, h_node, n_nodes);
  edge_mfma_kernel<<<2048, 256, 0, stream>>>(x_edge, eidx, W_edge, b_edge,
                                             h_node, gamma, beta, out, n_edges);
}

// Round 13
// 246.248 us; speedup vs baseline: 1.1080x; 1.0525x over previous
//
#include <hip/hip_runtime.h>

// DualEmbedding v13 == v9 (FINAL, champion 247us). v12's 2-deep pipeline
// reverted (+12us: VGPR pressure cost > latency-cover gain).
//
// Kernel A (node): h_node_bf16[node]: chunk(g,k) at byte k*64+g*16 holds
//   dims {16*(2k)+4g+j, 16*(2k+1)+4g+j}, j=0..3 (bf16).
// Kernel B (edge): out = LN(x_edge @ W_edge.T + b_edge + 0.5*(h[src]+h[dst]))
//
// MFMA mapping (16x16x32 bf16): C tile t, lane(c=lane&15,g=lane>>4), reg j =
//   C[dim=16t+4g+j][row base+c]  -> each lane owns all 128 dims of ONE row.
// LDS W swizzle: row r, 8-bf16 slot sigma stored at sigma^(r&7) — measured 0
// bank conflicts (R4/R6).
//
// Tuning history (all measured on MI355X):
//   v1 scalar f32/SGPR-dot: 1224us -> v2 MFMA per-lane-edge: 356 -> v3 bf16
//   permuted h + 1-deep gather pipeline: 295 -> v4 W in LDS: 276 -> v7 (k,g)
//   layout: 267 -> v9 (this): 247us.
//   Falsified: nt hints (294), launch_bounds cap (562, spills), node grid 3x
//   + native cvt (252), linearity merge (273), 2-deep pipeline (259).

typedef __attribute__((ext_vector_type(8))) short bf16x8;
typedef __attribute__((ext_vector_type(4))) float f32x4;

__device__ __forceinline__ short f2bf(float f) {          // RTNE f32->bf16
  unsigned u = __float_as_uint(f);
  u = (u + 0x7FFFu + ((u >> 16) & 1u)) >> 16;
  return (short)u;
}
__device__ __forceinline__ float bf2f(short s) {
  return __uint_as_float(((unsigned)(unsigned short)s) << 16);
}
__device__ __forceinline__ bf16x8 cvt8(const float* __restrict__ p) {
  const f32x4 a = *(const f32x4*)p;
  const f32x4 b = *(const f32x4*)(p + 4);
  bf16x8 r;
  r[0] = f2bf(a[0]); r[1] = f2bf(a[1]); r[2] = f2bf(a[2]); r[3] = f2bf(a[3]);
  r[4] = f2bf(b[0]); r[5] = f2bf(b[1]); r[6] = f2bf(b[2]); r[7] = f2bf(b[3]);
  return r;
}

// ---------------- node projection -> permuted bf16 table -------------------
__global__ __launch_bounds__(256) void node_mfma_kernel(
    const float* __restrict__ x_node,
    const float* __restrict__ W_node,
    const float* __restrict__ b_node,
    short* __restrict__ h_node,          // [N][128] bf16, (k,g)-chunked
    int n_nodes)
{
  __shared__ short Wlds[16384];         // 128 rows x 128 bf16 = 32 KB, swizzled
  __shared__ float blds[128];

  const int tid = threadIdx.x;
  {
    const int r = tid >> 1, h = tid & 1;      // row, which 64-col half
    const float* wr = W_node + (size_t)r * 128 + 64 * h;
#pragma unroll
    for (int q = 0; q < 8; ++q) {
      const bf16x8 v = cvt8(wr + 8 * q);
      const int slot = (8 * h + q) ^ (r & 7);
      *(bf16x8*)(&Wlds[r * 128 + slot * 8]) = v;
    }
    if (tid < 128) blds[tid] = b_node[tid];
  }
  __syncthreads();

  const int lane = tid & 63;
  const int c = lane & 15, g = lane >> 4;
  const int gw = blockIdx.x * 4 + (tid >> 6);
  const int nw = gridDim.x * 4;
  const int ntiles = (n_nodes + 15) >> 4;

  int woff[4];
#pragma unroll
  for (int s = 0; s < 4; ++s) woff[s] = c * 128 + ((4 * s + g) ^ (c & 7)) * 8;

  for (int tile = gw; tile < ntiles; tile += nw) {
    const int n0 = tile << 4;
    const int n = (n0 + c < n_nodes) ? n0 + c : n_nodes - 1;
    const float* xr = x_node + (size_t)n * 128;
    bf16x8 bx[4];
#pragma unroll
    for (int s = 0; s < 4; ++s) bx[s] = cvt8(xr + 32 * s + 8 * g);

    f32x4 acc[8];
#pragma unroll
    for (int t = 0; t < 8; ++t)
      acc[t] = *(const f32x4*)(blds + 16 * t + 4 * g);
#pragma unroll
    for (int t = 0; t < 8; ++t)
#pragma unroll
      for (int s = 0; s < 4; ++s) {
        const bf16x8 a = *(const bf16x8*)(&Wlds[t * 2048 + woff[s]]);
        acc[t] = __builtin_amdgcn_mfma_f32_16x16x32_bf16(a, bx[s], acc[t], 0, 0, 0);
      }

    if (n0 + c < n_nodes) {
      // chunk (g,k) at elements k*32+g*8 -> store instr k covers one
      // contiguous 64B line per row across g=0..3
      short* o = h_node + (size_t)(n0 + c) * 128 + g * 8;
#pragma unroll
      for (int k = 0; k < 4; ++k) {
        bf16x8 v;
#pragma unroll
        for (int j = 0; j < 4; ++j) {
          v[j]     = f2bf(acc[2 * k][j]);
          v[4 + j] = f2bf(acc[2 * k + 1][j]);
        }
        *(bf16x8*)(o + 32 * k) = v;
      }
    }
  }
}

// ---------------- fused edge: GEMM + gather + LayerNorm --------------------
__global__ __launch_bounds__(256) void edge_mfma_kernel(
    const float* __restrict__ x_edge,
    const int*   __restrict__ eidx,      // [2, E] int32
    const float* __restrict__ W_edge,
    const float* __restrict__ b_edge,
    const short* __restrict__ h_node,    // permuted bf16, (k,g)-chunked
    const float* __restrict__ gamma,
    const float* __restrict__ beta,
    float* __restrict__ out,
    int n_edges)
{
  __shared__ short Wlds[8192];          // 128 rows x 64 bf16 = 16 KB, swizzled
  __shared__ float plds[384];           // bias | gamma | beta

  const int tid = threadIdx.x;
  {
    const int r = tid >> 1, h = tid & 1;
    const float* wr = W_edge + (size_t)r * 64 + 32 * h;
#pragma unroll
    for (int q = 0; q < 4; ++q) {
      const bf16x8 v = cvt8(wr + 8 * q);
      const int slot = (4 * h + q) ^ (r & 7);
      *(bf16x8*)(&Wlds[r * 64 + slot * 8]) = v;
    }
    if (tid < 128) {
      plds[tid]       = b_edge[tid];
      plds[128 + tid] = gamma[tid];
      plds[256 + tid] = beta[tid];
    }
  }
  __syncthreads();

  const int lane = tid & 63;
  const int c = lane & 15, g = lane >> 4;
  const int gw = blockIdx.x * 4 + (tid >> 6);
  const int nw = gridDim.x * 4;
  const int ntiles = (n_edges + 15) >> 4;

  const int w0off = c * 64 + ((g) ^ (c & 7)) * 8;
  const int w1off = c * 64 + ((4 + g) ^ (c & 7)) * 8;

  if (gw >= ntiles) return;

  auto LOADIDX = [&](int tile, int& src, int& dst) {
    const int e = (tile * 16 + c < n_edges) ? tile * 16 + c : n_edges - 1;
    src = eidx[e];
    dst = eidx[n_edges + e];
  };
  auto LOADX = [&](int tile, bf16x8& b0, bf16x8& b1) {
    const int e = (tile * 16 + c < n_edges) ? tile * 16 + c : n_edges - 1;
    const float* xr = x_edge + (size_t)e * 64;
    b0 = cvt8(xr + 8 * g);
    b1 = cvt8(xr + 32 + 8 * g);
  };
  auto GATHER = [&](int src, int dst, bf16x8* vs, bf16x8* vd) {
    // (k,g)-chunks: instr k reads one contiguous 64B line per edge-row
    const short* hs = h_node + (size_t)src * 128 + g * 8;
    const short* hd = h_node + (size_t)dst * 128 + g * 8;
#pragma unroll
    for (int k = 0; k < 4; ++k) {
      vs[k] = *(const bf16x8*)(hs + 32 * k);
      vd[k] = *(const bf16x8*)(hd + 32 * k);
    }
  };

  // ---- pipeline state (single-buffered gathers, 1-deep) ------------------
  bf16x8 bx0, bx1, bxN0, bxN1;
  bf16x8 vs[4], vd[4];
  int srcN, dstN;

  {
    int src0, dst0;
    LOADIDX(gw, src0, dst0);
    LOADX(gw, bx0, bx1);
    GATHER(src0, dst0, vs, vd);
    LOADIDX(gw + nw, srcN, dstN);
  }

  for (int t = gw; t < ntiles; t += nw) {
    // 1) fold tile-t gathers into acc init (issued one iteration ago)
    f32x4 acc[8];
#pragma unroll
    for (int k = 0; k < 4; ++k)
#pragma unroll
      for (int j = 0; j < 4; ++j) {
        acc[2 * k][j]     = plds[16 * (2 * k) + 4 * g + j]
                          + 0.5f * (bf2f(vs[k][j]) + bf2f(vd[k][j]));
        acc[2 * k + 1][j] = plds[16 * (2 * k + 1) + 4 * g + j]
                          + 0.5f * (bf2f(vs[k][4 + j]) + bf2f(vd[k][4 + j]));
      }

    // 2) reuse freed vs/vd: issue gathers for tile t+nw
    GATHER(srcN, dstN, vs, vd);
    // 3) prefetch idx for t+2nw and x for t+nw
    LOADIDX(t + 2 * nw, srcN, dstN);
    LOADX(t + nw, bxN0, bxN1);

    // 4) GEMM for tile t (A from swizzled LDS)
#pragma unroll
    for (int tt = 0; tt < 8; ++tt) {
      const bf16x8 a0 = *(const bf16x8*)(&Wlds[tt * 1024 + w0off]);
      const bf16x8 a1 = *(const bf16x8*)(&Wlds[tt * 1024 + w1off]);
      acc[tt] = __builtin_amdgcn_mfma_f32_16x16x32_bf16(a0, bx0, acc[tt], 0, 0, 0);
      acc[tt] = __builtin_amdgcn_mfma_f32_16x16x32_bf16(a1, bx1, acc[tt], 0, 0, 0);
    }

    // 5) LayerNorm (dims of one edge split over lanes c, c+16, c+32, c+48)
    float s1 = 0.f;
#pragma unroll
    for (int tt = 0; tt < 8; ++tt)
      s1 += (acc[tt][0] + acc[tt][1]) + (acc[tt][2] + acc[tt][3]);
    s1 += __shfl_xor(s1, 16, 64);
    s1 += __shfl_xor(s1, 32, 64);
    const float mu = s1 * (1.f / 128.f);

    float s2 = 0.f;
#pragma unroll
    for (int tt = 0; tt < 8; ++tt)
#pragma unroll
      for (int j = 0; j < 4; ++j) {
        const float d = acc[tt][j] - mu;
        acc[tt][j] = d;
        s2 = fmaf(d, d, s2);
      }
    s2 += __shfl_xor(s2, 16, 64);
    s2 += __shfl_xor(s2, 32, 64);
    const float rstd = rsqrtf(s2 * (1.f / 128.f) + 1e-5f);

    // 6) store
    if (t * 16 + c < n_edges) {
      float* o = out + (size_t)(t * 16 + c) * 128 + 4 * g;
#pragma unroll
      for (int tt = 0; tt < 8; ++tt) {
        f32x4 r;
#pragma unroll
        for (int j = 0; j < 4; ++j)
          r[j] = fmaf(acc[tt][j] * rstd, plds[128 + 16 * tt + 4 * g + j],
                      plds[256 + 16 * tt + 4 * g + j]);
        *(f32x4*)(o + 16 * tt) = r;
      }
    }

    // 7) rotate x prefetch
    bx0 = bxN0; bx1 = bxN1;
  }
}

extern "C" void kernel_launch(void* const* d_in, const int* in_sizes, int n_in,
                              void* d_out, int out_size, void* d_ws, size_t ws_size,
                              hipStream_t stream) {
  const float* x_node = (const float*)d_in[0];
  const float* x_edge = (const float*)d_in[1];
  const int*   eidx   = (const int*)  d_in[2];
  const float* W_edge = (const float*)d_in[3];
  const float* b_edge = (const float*)d_in[4];
  const float* W_node = (const float*)d_in[5];
  const float* b_node = (const float*)d_in[6];
  const float* gamma  = (const float*)d_in[7];
  const float* beta   = (const float*)d_in[8];
  float* out = (float*)d_out;

  const int n_nodes = in_sizes[0] / 128;
  const int n_edges = in_sizes[2] / 2;

  short* h_node = (short*)d_ws;
  if (ws_size < (size_t)n_nodes * 128 * sizeof(short)) return;  // ws too small

  node_mfma_kernel<<<512, 256, 0, stream>>>(x_node, W_node, b_node, h_node, n_nodes);
  edge_mfma_kernel<<<2048, 256, 0, stream>>>(x_edge, eidx, W_edge, b_edge,
                                             h_node, gamma, beta, out, n_edges);
}